// Round 11
// baseline (1290.186 us; speedup 1.0000x reference)
//
#include <hip/hip_runtime.h>
#include <hip/hip_bf16.h>

#define EMB 768
#define HD 1024
#define D3 128
#define CTXN 512
#define BB 8
#define SS 64
#define NBLK 512

typedef __hip_bfloat16 bf16;
typedef __attribute__((ext_vector_type(8))) short short8v;
typedef __attribute__((ext_vector_type(4))) float f32x4;

__device__ __forceinline__ float fast_tanh(float x) {
  float e = __expf(2.f * x);
  return 1.f - 2.f * __builtin_amdgcn_rcpf(e + 1.f);
}

struct GDesc {
  const void* A;
  const bf16* BT;
  const int* arowmap;
  const float* addrow_f;
  const float* bias_f;
  float* Cf;
  bf16* Cb;
  bf16* CbT;
  float* brow_f;
  int M, N, K, lda, ldbt, ldct, af32, mtiles, blk0, nblks;
};

struct KP {
  const int* ids; const float* context; const float* emb;
  const float* W_in; const float* b_in; const float* W_s; const float* b_s;
  const float* W_att_in; const float* b_att_in; const float* W_att_h;
  const float* b_att_h; const float* V;
  float* ws; float* out; int* bar;
};

__device__ __forceinline__ GDesc mkd(const void* A, int af32, int lda,
                                     const int* arowmap, const bf16* BT, int ldbt,
                                     int M, int N, int K, const float* addrow_f,
                                     const float* bias_f, float* Cf, bf16* Cb,
                                     bf16* CbT, int ldct, float* brow_f) {
  GDesc d;
  d.A = A; d.BT = BT; d.arowmap = arowmap;
  d.addrow_f = addrow_f; d.bias_f = bias_f;
  d.Cf = Cf; d.Cb = Cb; d.CbT = CbT; d.brow_f = brow_f;
  d.M = M; d.N = N; d.K = K; d.lda = lda; d.ldbt = ldbt; d.ldct = ldct;
  d.af32 = af32;
  d.mtiles = (M + 31) >> 5;
  d.blk0 = 0;
  d.nblks = d.mtiles * (N >> 6);
  return d;
}

// device-wide generation barrier. Arrival = one RMW per block; spin = device-scope
// atomic LOAD (no write-back, no RMW serialization — r10's atomicAdd(bar,0) poll
// generated 387 MB of write traffic and 5x'd total time).
__device__ __forceinline__ void gbar(int* bar, int phase) {
  __syncthreads();
  if (threadIdx.x == 0) {
    __hip_atomic_fetch_add(bar, 1, __ATOMIC_ACQ_REL, __HIP_MEMORY_SCOPE_AGENT);
    int target = phase * NBLK;
    while (__hip_atomic_load(bar, __ATOMIC_ACQUIRE, __HIP_MEMORY_SCOPE_AGENT) < target)
      __builtin_amdgcn_s_sleep(8);
  }
  __syncthreads();
}

// ---- one 32x64 output tile, BK=128, XOR-swizzled dbuf LDS (r6-proven body) ----
__device__ void gemm_tile(const GDesc& d, int local, char* SM) {
  auto As = (bf16(*)[32][128])SM;              // 16 KB
  auto Bs = (bf16(*)[64][128])(SM + 16384);    // 32 KB
  __syncthreads();  // protect LDS reuse from previous tile/phase
  int mt = local % d.mtiles, nt = local / d.mtiles;
  int bm0 = mt * 32, bn0 = nt * 64;
  int tid = threadIdx.x, lane = tid & 63, wid = tid >> 6;
  int l16 = lane & 15, g = lane >> 4;
  int wm = (wid & 1) * 16, wn = (wid >> 1) * 32;
  int arow = tid >> 3, aseg = tid & 7;
  int brow = tid >> 2, bseg = tid & 3;
  f32x4 acc[2] = {};

  int agr = bm0 + arow;
  int asrc = (agr < d.M) ? (d.arowmap ? d.arowmap[agr] : agr) : -1;
  const float* Af = (const float*)d.A;
  const bf16* Ab = (const bf16*)d.A;

  float fa[16];
  short8v ba0 = {}, ba1 = {}, bb0 = {}, bb1 = {}, bb2 = {}, bb3 = {};
  int nk = d.K >> 7;

  auto LD = [&](int k0) {
    if (d.af32) {
      if (asrc >= 0) {
        const float* s = Af + (long)asrc * d.lda + k0 + aseg * 16;
#pragma unroll
        for (int j = 0; j < 16; ++j) fa[j] = s[j];
      } else {
#pragma unroll
        for (int j = 0; j < 16; ++j) fa[j] = 0.f;
      }
    } else {
      if (asrc >= 0) {
        const bf16* s = Ab + (long)asrc * d.lda + k0 + aseg * 16;
        ba0 = *(const short8v*)s;
        ba1 = *(const short8v*)(s + 8);
      } else {
        short8v z = {};
        ba0 = z; ba1 = z;
      }
    }
    const bf16* bsrc = d.BT + (long)(bn0 + brow) * d.ldbt + k0 + bseg * 32;
    bb0 = *(const short8v*)bsrc;
    bb1 = *(const short8v*)(bsrc + 8);
    bb2 = *(const short8v*)(bsrc + 16);
    bb3 = *(const short8v*)(bsrc + 24);
  };
  auto ST = [&](int buf) {
    int rs = arow & 7;
    if (d.af32) {
      bf16 t8[16];
#pragma unroll
      for (int j = 0; j < 16; ++j) t8[j] = __float2bfloat16(fa[j]);
      *(short8v*)&As[buf][arow][((2 * aseg) ^ rs) * 8] = *(short8v*)t8;
      *(short8v*)&As[buf][arow][((2 * aseg + 1) ^ rs) * 8] = *(short8v*)(t8 + 8);
    } else {
      *(short8v*)&As[buf][arow][((2 * aseg) ^ rs) * 8] = ba0;
      *(short8v*)&As[buf][arow][((2 * aseg + 1) ^ rs) * 8] = ba1;
    }
    int rb = brow & 7;
    *(short8v*)&Bs[buf][brow][((4 * bseg) ^ rb) * 8] = bb0;
    *(short8v*)&Bs[buf][brow][((4 * bseg + 1) ^ rb) * 8] = bb1;
    *(short8v*)&Bs[buf][brow][((4 * bseg + 2) ^ rb) * 8] = bb2;
    *(short8v*)&Bs[buf][brow][((4 * bseg + 3) ^ rb) * 8] = bb3;
  };

  LD(0);
  ST(0);
  __syncthreads();
  for (int it = 0; it < nk; ++it) {
    int cur = it & 1;
    if (it + 1 < nk) LD((it + 1) << 7);
    int ar = wm + l16;
    int ars = ar & 7;
#pragma unroll
    for (int kf = 0; kf < 4; ++kf) {
      short8v a = *(const short8v*)&As[cur][ar][((kf * 4 + g) ^ ars) * 8];
#pragma unroll
      for (int j = 0; j < 2; ++j) {
        int br = wn + j * 16 + l16;
        short8v b = *(const short8v*)&Bs[cur][br][((kf * 4 + g) ^ (br & 7)) * 8];
        acc[j] = __builtin_amdgcn_mfma_f32_16x16x32_bf16(a, b, acc[j], 0, 0, 0);
      }
    }
    if (it + 1 < nk) ST(cur ^ 1);
    __syncthreads();
  }

  float* Cs = (float*)(SM + 16384);  // overlay Bs: [64][33] floats
  bool doT = (d.CbT != nullptr);
#pragma unroll
  for (int j = 0; j < 2; ++j)
#pragma unroll
    for (int r = 0; r < 4; ++r) {
      int gl = wm + g * 4 + r, cl = wn + j * 16 + l16;
      int grow = bm0 + gl, gcol = bn0 + cl;
      float v = acc[j][r];
      if (d.bias_f) v += d.bias_f[gcol];
      if (d.addrow_f && grow == d.M - 1) v += d.addrow_f[gcol];
      if (grow < d.M) {
        if (d.Cf) d.Cf[(long)grow * d.N + gcol] = v;
        if (d.Cb) d.Cb[(long)grow * d.N + gcol] = __float2bfloat16(v);
        if (d.brow_f && grow == d.M - 1) d.brow_f[gcol] = v;
      }
      if (doT) Cs[cl * 33 + gl] = v;
    }
  if (doT) {
    __syncthreads();
    int ctrows = d.M < 1024 ? d.M : 1024;
    int n = tid >> 2, ms = (tid & 3) * 8;
    int gm0 = bm0 + ms;
    bf16 t8[8];
#pragma unroll
    for (int jj = 0; jj < 8; ++jj) t8[jj] = __float2bfloat16(Cs[n * 33 + ms + jj]);
    if (gm0 + 7 < ctrows) {
      *(short8v*)&d.CbT[(long)(bn0 + n) * d.ldct + gm0] = *(short8v*)t8;
    } else {
#pragma unroll
      for (int jj = 0; jj < 8; ++jj)
        if (gm0 + jj < ctrows) d.CbT[(long)(bn0 + n) * d.ldct + gm0 + jj] = t8[jj];
    }
  }
}

__device__ void runbatch(GDesc* ds, int nd, char* SM) {
  int c = 0;
  for (int i = 0; i < nd; ++i) { ds[i].blk0 = c; c += ds[i].nblks; }
  for (int t = blockIdx.x; t < c; t += NBLK) {
    int i = 0;
    for (int j = 1; j < nd; ++j)
      if (t >= ds[j].blk0) i = j;
    gemm_tile(ds[i], t - ds[i].blk0, SM);
  }
}

__device__ void TPdev(const float* src, int R, int C, bf16* dst, int tr, int tc,
                      char* SM) {
  auto tl = (bf16(*)[65])SM;
  int tid = threadIdx.x;
  int r0 = tr * 64, c0 = tc * 64;
  {
    int r = tid >> 2, cs = (tid & 3) * 16;
    const float* s = src + (long)(r0 + r) * C + c0 + cs;
#pragma unroll
    for (int j = 0; j < 16; ++j) tl[cs + j][r] = __float2bfloat16(s[j]);
  }
  __syncthreads();
  {
    int c = tid >> 2, rs = (tid & 3) * 16;
    bf16 o[16];
#pragma unroll
    for (int j = 0; j < 16; ++j) o[j] = tl[c][rs + j];
    *(short8v*)&dst[(long)(c0 + c) * R + r0 + rs] = *(short8v*)&o[0];
    *(short8v*)&dst[(long)(c0 + c) * R + r0 + rs + 8] = *(short8v*)&o[8];
  }
}

__global__ __launch_bounds__(256) void megak(KP p) {
  __shared__ __align__(16) char SM[49664];
  int tid = threadIdx.x;

  float* ws = p.ws;
  float* ctxp = ws;
  float* Yf = ws + 524288;
  float* qF = ws + 1705088;
  float* qH = ws + 1770624;
  float* qb = ws + 1836160;
  float* brow2 = ws + 1836288;
  float* brow4 = ws + 1837312;
  float* brow8 = ws + 1838336;
  float* brow16 = ws + 1839360;
  float* brow32 = ws + 1840384;
  int* rowmap = (int*)(ws + 1841408);
  bf16* Mb0 = (bf16*)(ws + 1841920);
  bf16* Mb0T = Mb0 + 1049600;
  bf16* Mb1 = Mb0T + 1048576;
  bf16* Mb1T = Mb1 + 1049600;
  bf16* Mb2 = Mb1T + 1048576;
  bf16* Mb2T = Mb2 + 1049600;
  bf16* Mb3 = Mb2T + 1048576;
  bf16* Mb3T = Mb3 + 1049600;
  bf16* YT = Mb3T + 1048576;
  bf16* WahT = YT + 9 * 131072;
  bf16* WaiT = WahT + 131072;
  bf16* WcT = WaiT + 131072;
  bf16* Gb = WcT + 131072;

  auto Yfr = [&](int r) { return Yf + (long)r * 131200; };
  auto YTs = [&](int r) { return YT + (long)r * 131072; };

  // ---------------- P0: casts / transposes / g0 / qb / rowmap
  for (int it = blockIdx.x; it < 612; it += NBLK) {
    __syncthreads();
    if (it < 256) {
      long base = (long)it * 4096;
      for (int i = tid; i < 4096; i += 256)
        Mb0[base + i] = __float2bfloat16(p.W_s[base + i]);
    } else if (it == 256) {
      for (int i = tid; i < HD; i += 256)
        Mb0[(long)HD * HD + i] = __float2bfloat16(p.b_s[i]);
    } else if (it < 513) {
      int t = it - 257;
      TPdev(p.W_s, 1024, 1024, Mb0T, t >> 4, t & 15, SM);
    } else if (it < 545) {
      int t = it - 513;
      TPdev(p.W_att_in + (long)1024 * D3, 1024, 128, YTs(0), t >> 1, t & 1, SM);
    } else if (it < 577) {
      int t = it - 545;
      TPdev(p.W_att_h, 1024, 128, WahT, t >> 1, t & 1, SM);
    } else if (it < 609) {
      int t = it - 577;
      TPdev(p.W_att_in, 1024, 128, WaiT, t >> 1, t & 1, SM);
    } else if (it == 609) {
      for (int i = tid; i < BB * HD; i += 256) {
        int b = i >> 10, k = i & 1023;
        Gb[i] = __float2bfloat16(p.context[((long)b * CTXN + CTXN - 1) * HD + k]);
      }
    } else if (it == 610) {
      auto red = (float(*)[128])(SM + 16384);
      int dd = tid & 127, h = tid >> 7;
      float acc = 0.f;
      for (int k = h * 512; k < h * 512 + 512; ++k)
        acc += p.b_in[k] * p.W_att_in[k * D3 + dd];
      red[h][dd] = acc;
      __syncthreads();
      if (h == 0) qb[dd] = red[0][dd] + red[1][dd] + p.b_att_in[dd];
    } else {
      for (int i = tid; i < 512; i += 256) {
        int t = i >> 3, b = i & 7;
        rowmap[i] = p.ids[b * SS + t];
      }
    }
  }
  gbar(p.bar, 1);

  // ---------------- P1: M2, Z1, ctx_proj, WcT
  {
    GDesc ds[4];
    ds[0] = mkd(Mb0, 0, 1024, nullptr, Mb0T, 1024, 1025, 1024, 1024, p.b_s, nullptr, nullptr, Mb1, Mb1T, 1024, brow2);
    ds[1] = mkd(Mb0, 0, 1024, nullptr, YTs(0), 1024, 1025, 128, 1024, nullptr, nullptr, Yfr(1), nullptr, YTs(1), 1024, nullptr);
    ds[2] = mkd(p.context, 1, 1024, nullptr, WahT, 1024, 4096, 128, 1024, nullptr, p.b_att_h, ctxp, nullptr, nullptr, 0, nullptr);
    ds[3] = mkd(p.W_in, 1, 1024, nullptr, WaiT, 1024, 768, 128, 1024, nullptr, nullptr, nullptr, nullptr, WcT, 768, nullptr);
    runbatch(ds, 4, SM);
  }
  gbar(p.bar, 2);

  // ---------------- P2: M4, Z2, Z3, qF
  {
    GDesc ds[4];
    ds[0] = mkd(Mb1, 0, 1024, nullptr, Mb1T, 1024, 1025, 1024, 1024, brow2, nullptr, nullptr, Mb2, Mb2T, 1024, brow4);
    ds[1] = mkd(Mb1, 0, 1024, nullptr, YTs(0), 1024, 1025, 128, 1024, nullptr, nullptr, Yfr(2), nullptr, YTs(2), 1024, nullptr);
    ds[2] = mkd(Mb1, 0, 1024, nullptr, YTs(1), 1024, 1025, 128, 1024, Yfr(1) + 131072, nullptr, Yfr(3), nullptr, YTs(3), 1024, nullptr);
    ds[3] = mkd(p.emb, 1, 768, rowmap, WcT, 768, 512, 128, 768, nullptr, qb, qF, nullptr, nullptr, 0, nullptr);
    runbatch(ds, 4, SM);
  }
  gbar(p.bar, 3);

  // ---------------- P3: M8, Z4..Z7
  {
    GDesc ds[5];
    ds[0] = mkd(Mb2, 0, 1024, nullptr, Mb2T, 1024, 1025, 1024, 1024, brow4, nullptr, nullptr, Mb3, Mb3T, 1024, brow8);
    for (int s = 0; s < 4; ++s)
      ds[1 + s] = mkd(Mb2, 0, 1024, nullptr, YTs(s), 1024, 1025, 128, 1024,
                      (s == 0) ? nullptr : (Yfr(s) + 131072), nullptr, Yfr(4 + s),
                      nullptr, YTs(4 + s), 1024, nullptr);
    runbatch(ds, 5, SM);
  }
  gbar(p.bar, 4);

  // ---------------- P4: M16, Z8, g1
  {
    GDesc ds[3];
    ds[0] = mkd(Mb3, 0, 1024, nullptr, Mb3T, 1024, 1025, 1024, 1024, brow8, nullptr, nullptr, Mb1, Mb1T, 1024, brow16);
    ds[1] = mkd(Mb3, 0, 1024, nullptr, YTs(0), 1024, 1025, 128, 1024, nullptr, nullptr, Yfr(8), nullptr, YTs(8), 1024, nullptr);
    ds[2] = mkd(Gb, 0, 1024, nullptr, Mb3T, 1024, 8, 1024, 1024, nullptr, brow8, nullptr, Gb + 8192, nullptr, 0, nullptr);
    runbatch(ds, 3, SM);
  }
  gbar(p.bar, 5);

  // ---------------- P5: M32, [g2,g3]
  {
    GDesc ds[2];
    ds[0] = mkd(Mb1, 0, 1024, nullptr, Mb1T, 1024, 1025, 1024, 1024, brow16, nullptr, nullptr, Mb2, Mb2T, 1024, brow32);
    ds[1] = mkd(Gb, 0, 1024, nullptr, Mb1T, 1024, 16, 1024, 1024, nullptr, brow16, nullptr, Gb + 16384, nullptr, 0, nullptr);
    runbatch(ds, 2, SM);
  }
  gbar(p.bar, 6);

  // ---------------- P6: [g4..g7]
  {
    GDesc ds[1];
    ds[0] = mkd(Gb, 0, 1024, nullptr, Mb2T, 1024, 32, 1024, 1024, nullptr, brow32, nullptr, Gb + 32768, nullptr, 0, nullptr);
    runbatch(ds, 1, SM);
  }
  gbar(p.bar, 7);

  // ---------------- P7: qH r=1..8
  {
    GDesc ds[8];
    for (int r = 1; r <= 8; ++r)
      ds[r - 1] = mkd(Gb, 0, 1024, nullptr, YTs(r), 1024, 64, 128, 1024, nullptr,
                      Yfr(r) + 131072, qH + (long)(r - 1) * 8192, nullptr, nullptr, 0,
                      nullptr);
    runbatch(ds, 8, SM);
  }
  gbar(p.bar, 8);

  // ---------------- P8: katt
  {
    auto lq = (float(*)[128])SM;                    // 16 KB
    auto lc = (float(*)[132])(SM + 16384);          // 16.9 KB
    float* lv = (float*)(SM + 33792);               // 512 B
    for (int it = blockIdx.x; it < 256; it += NBLK) {
      __syncthreads();
      int b = it >> 5, tt = (it >> 4) & 1, ct = it & 15;
      int t0 = tt * 32, c0 = ct * 32;
      for (int i = tid; i < 32 * 128; i += 256) {
        int r = i >> 7, d = i & 127;
        int t = t0 + r;
        lq[r][d] = qF[((long)t * 8 + b) * 128 + d] +
                   qH[(((long)(t & 7)) * 64 + (t >> 3) * 8 + b) * 128 + d];
        lc[r][d] = ctxp[((long)b * CTXN + c0 + r) * D3 + d];
      }
      if (tid < 128) lv[tid] = p.V[tid];
      __syncthreads();
      int cl = tid & 31, tg = tid >> 5;
      float r4[4] = {0.f, 0.f, 0.f, 0.f};
      for (int d4 = 0; d4 < 32; ++d4) {
        float4 cv = *reinterpret_cast<const float4*>(&lc[cl][d4 * 4]);
        float4 vv = *reinterpret_cast<const float4*>(&lv[d4 * 4]);
#pragma unroll
        for (int u = 0; u < 4; ++u) {
          int t = tg + u * 8;
          float4 qv = *reinterpret_cast<const float4*>(&lq[t][d4 * 4]);
          r4[u] = fmaf(vv.x, fast_tanh(qv.x + cv.x), r4[u]);
          r4[u] = fmaf(vv.y, fast_tanh(qv.y + cv.y), r4[u]);
          r4[u] = fmaf(vv.z, fast_tanh(qv.z + cv.z), r4[u]);
          r4[u] = fmaf(vv.w, fast_tanh(qv.w + cv.w), r4[u]);
        }
      }
#pragma unroll
      for (int u = 0; u < 4; ++u) {
        int t = tg + u * 8;
        p.out[((long)b * SS + (t0 + t)) * CTXN + c0 + cl] = r4[u];
      }
      if (it == 0) {
        for (int i = tid; i < SS * BB; i += 256)
          p.out[(long)BB * SS * CTXN + i] = 0.f;
      }
    }
  }
}

extern "C" void kernel_launch(void* const* d_in, const int* in_sizes, int n_in,
                              void* d_out, int out_size, void* d_ws, size_t ws_size,
                              hipStream_t stream) {
  KP p;
  p.ids = (const int*)d_in[0];
  p.context = (const float*)d_in[4];
  p.emb = (const float*)d_in[5];
  p.W_in = (const float*)d_in[6];
  p.b_in = (const float*)d_in[7];
  p.W_s = (const float*)d_in[8];
  p.b_s = (const float*)d_in[9];
  p.W_att_in = (const float*)d_in[10];
  p.b_att_in = (const float*)d_in[11];
  p.W_att_h = (const float*)d_in[12];
  p.b_att_h = (const float*)d_in[13];
  p.V = (const float*)d_in[14];
  p.ws = (float*)d_ws;
  p.out = (float*)d_out;
  p.bar = (int*)((char*)d_ws + ws_size - 64);

  (void)hipMemsetAsync(p.bar, 0, 4, stream);
  megak<<<dim3(NBLK), dim3(256), 0, stream>>>(p);
}

// Round 12
// 210.360 us; speedup vs baseline: 6.1332x; 6.1332x over previous
//
#include <hip/hip_runtime.h>
#include <hip/hip_bf16.h>

#define EMB 768
#define HD 1024
#define D3 128
#define CTXN 512
#define BB 8
#define SS 64

typedef __hip_bfloat16 bf16;
typedef __attribute__((ext_vector_type(8))) short short8v;
typedef __attribute__((ext_vector_type(4))) float f32x4;

__device__ __forceinline__ float fast_tanh(float x) {
  float e = __expf(2.f * x);
  return 1.f - 2.f * __builtin_amdgcn_rcpf(e + 1.f);
}

struct GDesc {
  const void* A;            // [M][K] fp32 (af32) or bf16
  const float* alast;       // optional fp32 source for row M-1 (b_s)
  const bf16* BT;           // bmode0: [N][K] bf16 pre-transposed
  const float* Bf32;        // bmode1: [K][N] fp32 row-major (stage-transpose)
  const int* ids;           // amode3 gather
  const float* addrow_f;    // added to row M-1 only
  const float* bias_f;      // added to all rows
  float* Cf; bf16* Cb; bf16* CbT; float* brow_f;
  int M, N, K, lda, ldbt, ldct, af32, amode, bmode, mtiles, blk0, nblks;
};
struct GBatch { GDesc d[12]; int nd; };

// gemmz: 32x64 tile, BK=128, XOR-swizzled dbuf LDS, XCD-chunked block swizzle.
__global__ __launch_bounds__(256) void gemmz(GBatch bat) {
  // XCD swizzle (bijective): blocks with equal blockIdx%8 (same XCD) get a
  // contiguous chunk of logical tile ids -> B/A panels stay in one L2.
  int nwg = gridDim.x, orig = blockIdx.x;
  int q8 = nwg >> 3, r8 = nwg & 7;
  int xcd = orig & 7, idx = orig >> 3;
  int bx = (xcd < r8 ? xcd * (q8 + 1) : r8 * (q8 + 1) + (xcd - r8) * q8) + idx;

  GDesc d = bat.d[0];
  for (int i = 1; i < bat.nd; ++i)
    if (bx >= bat.d[i].blk0) d = bat.d[i];
  int local = bx - d.blk0;
  int mt = local % d.mtiles, nt = local / d.mtiles;
  int bm0 = mt * 32, bn0 = nt * 64;

  __shared__ bf16 As[2][32][128];
  __shared__ bf16 Bs[2][64][128];
  int tid = threadIdx.x, lane = tid & 63, wid = tid >> 6;
  int l16 = lane & 15, g = lane >> 4;
  int wm = (wid & 1) * 16, wn = (wid >> 1) * 32;
  int arow = tid >> 3, aseg = tid & 7;     // A: 32 rows x 8 segs of 16
  int brow = tid >> 2, bseg = tid & 3;     // B bmode0: 64 rows x 4 segs of 32
  int kr = tid >> 1, nh = (tid & 1) * 32;  // B bmode1: 128 k-rows x 2 n-halves
  f32x4 acc[2] = {};

  int agr = bm0 + arow;
  const float* afp = nullptr;
  const bf16* abf = nullptr;
  if (agr < d.M) {
    long asrc;
    if (d.amode == 2) asrc = (long)agr * CTXN + (CTXN - 1);
    else if (d.amode == 3) asrc = d.ids[(agr & 7) * SS + (agr >> 3)];
    else asrc = agr;
    if (d.alast && agr == d.M - 1) afp = d.alast;
    else if (d.af32) afp = (const float*)d.A + asrc * d.lda;
    else abf = (const bf16*)d.A + asrc * d.lda;
  }

  float fa[16] = {};
  short8v ba0 = {}, ba1 = {};
  short8v bb0 = {}, bb1 = {}, bb2 = {}, bb3 = {};
  float fb[32];
  int nk = d.K >> 7;

  auto LD = [&](int k0) {
    if (afp) {
      const float* s = afp + k0 + aseg * 16;
#pragma unroll
      for (int j = 0; j < 16; ++j) fa[j] = s[j];
    } else if (abf) {
      const bf16* s = abf + k0 + aseg * 16;
      ba0 = *(const short8v*)s;
      ba1 = *(const short8v*)(s + 8);
    }
    if (d.bmode == 0) {
      const bf16* bsrc = d.BT + (long)(bn0 + brow) * d.ldbt + k0 + bseg * 32;
      bb0 = *(const short8v*)bsrc;
      bb1 = *(const short8v*)(bsrc + 8);
      bb2 = *(const short8v*)(bsrc + 16);
      bb3 = *(const short8v*)(bsrc + 24);
    } else {
      const float* s = d.Bf32 + (long)(k0 + kr) * d.ldbt + bn0 + nh;
#pragma unroll
      for (int j = 0; j < 32; ++j) fb[j] = s[j];
    }
  };
  auto ST = [&](int buf) {
    int rs = arow & 7;
    if (d.af32) {
      bf16 t8[16];
#pragma unroll
      for (int j = 0; j < 16; ++j) t8[j] = __float2bfloat16(fa[j]);
      *(short8v*)&As[buf][arow][((2 * aseg) ^ rs) * 8] = *(short8v*)t8;
      *(short8v*)&As[buf][arow][((2 * aseg + 1) ^ rs) * 8] = *(short8v*)(t8 + 8);
    } else {
      *(short8v*)&As[buf][arow][((2 * aseg) ^ rs) * 8] = ba0;
      *(short8v*)&As[buf][arow][((2 * aseg + 1) ^ rs) * 8] = ba1;
    }
    if (d.bmode == 0) {
      int rb = brow & 7;
      *(short8v*)&Bs[buf][brow][((4 * bseg) ^ rb) * 8] = bb0;
      *(short8v*)&Bs[buf][brow][((4 * bseg + 1) ^ rb) * 8] = bb1;
      *(short8v*)&Bs[buf][brow][((4 * bseg + 2) ^ rb) * 8] = bb2;
      *(short8v*)&Bs[buf][brow][((4 * bseg + 3) ^ rb) * 8] = bb3;
    } else {
      int c = kr >> 3, w = kr & 7;
#pragma unroll
      for (int j = 0; j < 32; ++j) {
        int n = nh + j;
        Bs[buf][n][((c ^ (n & 7)) << 3) | w] = __float2bfloat16(fb[j]);
      }
    }
  };

  LD(0);
  ST(0);
  __syncthreads();
  for (int it = 0; it < nk; ++it) {
    int cur = it & 1;
    if (it + 1 < nk) LD((it + 1) << 7);
    int ar = wm + l16;
    int ars = ar & 7;
#pragma unroll
    for (int kf = 0; kf < 4; ++kf) {
      short8v a = *(const short8v*)&As[cur][ar][((kf * 4 + g) ^ ars) * 8];
#pragma unroll
      for (int j = 0; j < 2; ++j) {
        int br = wn + j * 16 + l16;
        short8v b = *(const short8v*)&Bs[cur][br][((kf * 4 + g) ^ (br & 7)) * 8];
        acc[j] = __builtin_amdgcn_mfma_f32_16x16x32_bf16(a, b, acc[j], 0, 0, 0);
      }
    }
    if (it + 1 < nk) ST(cur ^ 1);
    __syncthreads();
  }

  float* Cs = (float*)&Bs[0][0][0];  // overlay: [64][33] floats
  bool doT = (d.CbT != nullptr);
#pragma unroll
  for (int j = 0; j < 2; ++j)
#pragma unroll
    for (int r = 0; r < 4; ++r) {
      int gl = wm + g * 4 + r, cl = wn + j * 16 + l16;
      int grow = bm0 + gl, gcol = bn0 + cl;
      float v = acc[j][r];
      if (d.bias_f) v += d.bias_f[gcol];
      if (d.addrow_f && grow == d.M - 1) v += d.addrow_f[gcol];
      if (grow < d.M) {
        if (d.Cf) d.Cf[(long)grow * d.N + gcol] = v;
        if (d.Cb) d.Cb[(long)grow * d.N + gcol] = __float2bfloat16(v);
        if (d.brow_f && grow == d.M - 1) d.brow_f[gcol] = v;
      }
      if (doT) Cs[cl * 33 + gl] = v;
    }
  if (doT) {
    __syncthreads();
    int ctrows = d.M < 1024 ? d.M : 1024;
    int n = tid >> 2, ms = (tid & 3) * 8;
    int gm0 = bm0 + ms;
    bf16 t8[8];
#pragma unroll
    for (int jj = 0; jj < 8; ++jj) t8[jj] = __float2bfloat16(Cs[n * 33 + ms + jj]);
    if (gm0 + 7 < ctrows) {
      *(short8v*)&d.CbT[(long)(bn0 + n) * d.ldct + gm0] = *(short8v*)t8;
    } else {
#pragma unroll
      for (int jj = 0; jj < 8; ++jj)
        if (gm0 + jj < ctrows) d.CbT[(long)(bn0 + n) * d.ldct + gm0 + jj] = t8[jj];
    }
  }
}

// katt: out[b][t][c] = sum_d V[d]*tanh(qF[t*8+b][d] + qH[t&7][(t>>3)*8+b][d] + ctxp[b][c][d])
__global__ __launch_bounds__(256) void katt(const float* __restrict__ qF,
                                            const float* __restrict__ qH,
                                            const float* __restrict__ ctxp,
                                            const float* __restrict__ V,
                                            float* __restrict__ out) {
  int blk = blockIdx.x;
  int b = blk >> 5, tt = (blk >> 4) & 1, ct = blk & 15;
  int t0 = tt * 32, c0 = ct * 32;
  int tid = threadIdx.x;
  __shared__ float lq[32][128];
  __shared__ float lc[32][132];
  __shared__ float lv[128];
  for (int i = tid; i < 32 * 128; i += 256) {
    int r = i >> 7, d = i & 127;
    int t = t0 + r;
    lq[r][d] = qF[((long)t * 8 + b) * 128 + d] +
               qH[(((long)(t & 7)) * 64 + (t >> 3) * 8 + b) * 128 + d];
    lc[r][d] = ctxp[((long)b * CTXN + c0 + r) * D3 + d];
  }
  if (tid < 128) lv[tid] = V[tid];
  __syncthreads();
  int cl = tid & 31, tg = tid >> 5;
  float r4[4] = {0.f, 0.f, 0.f, 0.f};
  for (int d4 = 0; d4 < 32; ++d4) {
    float4 cv = *reinterpret_cast<const float4*>(&lc[cl][d4 * 4]);
    float4 vv = *reinterpret_cast<const float4*>(&lv[d4 * 4]);
#pragma unroll
    for (int u = 0; u < 4; ++u) {
      int t = tg + u * 8;
      float4 qv = *reinterpret_cast<const float4*>(&lq[t][d4 * 4]);
      r4[u] = fmaf(vv.x, fast_tanh(qv.x + cv.x), r4[u]);
      r4[u] = fmaf(vv.y, fast_tanh(qv.y + cv.y), r4[u]);
      r4[u] = fmaf(vv.z, fast_tanh(qv.z + cv.z), r4[u]);
      r4[u] = fmaf(vv.w, fast_tanh(qv.w + cv.w), r4[u]);
    }
  }
#pragma unroll
  for (int u = 0; u < 4; ++u) {
    int t = tg + u * 8;
    out[((long)b * SS + (t0 + t)) * CTXN + c0 + cl] = r4[u];
  }
  if (blk == 0) {
    for (int i = tid; i < SS * BB; i += 256) out[(long)BB * SS * CTXN + i] = 0.f;
  }
}

static inline GDesc mkD(const void* A, int af32, int amode, int lda,
                        const float* alast, const int* ids, const bf16* BT,
                        const float* Bf32, int ldbt, int M, int N, int K,
                        const float* addrow_f, const float* bias_f, float* Cf,
                        bf16* Cb, bf16* CbT, int ldct, float* brow_f, int blk0) {
  GDesc d;
  d.A = A; d.alast = alast; d.BT = BT; d.Bf32 = Bf32; d.ids = ids;
  d.addrow_f = addrow_f; d.bias_f = bias_f;
  d.Cf = Cf; d.Cb = Cb; d.CbT = CbT; d.brow_f = brow_f;
  d.M = M; d.N = N; d.K = K; d.lda = lda; d.ldbt = ldbt; d.ldct = ldct;
  d.af32 = af32; d.amode = amode; d.bmode = Bf32 ? 1 : 0;
  d.mtiles = (M + 31) >> 5;
  d.blk0 = blk0;
  d.nblks = d.mtiles * (N >> 6);
  return d;
}

extern "C" void kernel_launch(void* const* d_in, const int* in_sizes, int n_in,
                              void* d_out, int out_size, void* d_ws, size_t ws_size,
                              hipStream_t stream) {
  const int* ids = (const int*)d_in[0];
  const float* context = (const float*)d_in[4];
  const float* emb = (const float*)d_in[5];
  const float* W_in = (const float*)d_in[6];
  const float* b_in = (const float*)d_in[7];
  const float* W_s = (const float*)d_in[8];
  const float* b_s = (const float*)d_in[9];
  const float* W_att_in = (const float*)d_in[10];
  const float* b_att_in = (const float*)d_in[11];
  const float* W_att_h = (const float*)d_in[12];
  const float* b_att_h = (const float*)d_in[13];
  const float* V = (const float*)d_in[14];
  const float* Wa_bot = W_att_in + (long)1024 * D3;

  float* ws = (float*)d_ws;
  float* ctxp = ws;                 // [4096][128]
  float* qF = ws + 524288;          // [512][128]
  float* qH = ws + 589824;          // [8][64][128]
  float* qb = ws + 655360;          // 128
  float* brow2 = ws + 655488;       // 1024 each
  float* brow4 = ws + 656512;
  float* brow8 = ws + 657536;
  float* brow16 = ws + 658560;
  float* brow32 = ws + 659584;
  float* zb = ws + 660608;          // 9*128; zb(r) = zb + r*128
  bf16* bfp = (bf16*)(ws + 661760);
  bf16* Mb1 = bfp;                  // 1025*1024
  bf16* Mb1T = Mb1 + 1049600;       // 1024*1024
  bf16* Mb2 = Mb1T + 1048576;
  bf16* Mb2T = Mb2 + 1049600;
  bf16* Mb3 = Mb2T + 1048576;
  bf16* Mb3T = Mb3 + 1049600;
  bf16* YT = Mb3T + 1048576;        // 9 slots * 131072 (slot 0 unused)
  bf16* WcT = YT + 9 * 131072;      // [128][768]
  bf16* Gb = WcT + 98304;           // [64][1024] (rows 8..63 used)
  float* out = (float*)d_out;

  auto YTs = [&](int r) { return YT + (long)r * 131072; };
  auto zbr = [&](int r) { return zb + (long)r * 128; };

  // L1: M2 (fp32 inputs), Z1, ctx_proj, Wc^T, qb
  {
    GBatch bt{}; int c = 0;
    bt.d[0] = mkD(W_s, 1, 0, 1024, b_s, nullptr, nullptr, W_s, 1024, 1025, 1024, 1024, b_s, nullptr, nullptr, Mb1, Mb1T, 1024, brow2, c); c += bt.d[0].nblks;
    bt.d[1] = mkD(W_s, 1, 0, 1024, b_s, nullptr, nullptr, Wa_bot, 128, 1025, 128, 1024, nullptr, nullptr, nullptr, nullptr, YTs(1), 1024, zbr(1), c); c += bt.d[1].nblks;
    bt.d[2] = mkD(context, 1, 0, 1024, nullptr, nullptr, nullptr, W_att_h, 128, 4096, 128, 1024, nullptr, b_att_h, ctxp, nullptr, nullptr, 0, nullptr, c); c += bt.d[2].nblks;
    bt.d[3] = mkD(W_in, 1, 0, 1024, nullptr, nullptr, nullptr, W_att_in, 128, 768, 128, 1024, nullptr, nullptr, nullptr, nullptr, WcT, 768, nullptr, c); c += bt.d[3].nblks;
    bt.d[4] = mkD(b_in, 1, 0, 1024, nullptr, nullptr, nullptr, W_att_in, 128, 1, 128, 1024, nullptr, b_att_in, qb, nullptr, nullptr, 0, nullptr, c); c += bt.d[4].nblks;
    bt.nd = 5;
    gemmz<<<dim3(c), dim3(256), 0, stream>>>(bt);
  }
  // L2: M4, Z2 (B=Z0 fp32), Z3 (B=YT1), qF
  {
    GBatch bt{}; int c = 0;
    bt.d[0] = mkD(Mb1, 0, 0, 1024, nullptr, nullptr, Mb1T, nullptr, 1024, 1025, 1024, 1024, brow2, nullptr, nullptr, Mb2, Mb2T, 1024, brow4, c); c += bt.d[0].nblks;
    bt.d[1] = mkD(Mb1, 0, 0, 1024, nullptr, nullptr, nullptr, Wa_bot, 128, 1025, 128, 1024, nullptr, nullptr, nullptr, nullptr, YTs(2), 1024, zbr(2), c); c += bt.d[1].nblks;
    bt.d[2] = mkD(Mb1, 0, 0, 1024, nullptr, nullptr, YTs(1), nullptr, 1024, 1025, 128, 1024, zbr(1), nullptr, nullptr, nullptr, YTs(3), 1024, zbr(3), c); c += bt.d[2].nblks;
    bt.d[3] = mkD(emb, 1, 3, 768, nullptr, ids, WcT, nullptr, 768, 512, 128, 768, nullptr, qb, qF, nullptr, nullptr, 0, nullptr, c); c += bt.d[3].nblks;
    bt.nd = 4;
    gemmz<<<dim3(c), dim3(256), 0, stream>>>(bt);
  }
  // L3: M8, Z4..Z7
  {
    GBatch bt{}; int c = 0;
    bt.d[0] = mkD(Mb2, 0, 0, 1024, nullptr, nullptr, Mb2T, nullptr, 1024, 1025, 1024, 1024, brow4, nullptr, nullptr, Mb3, Mb3T, 1024, brow8, c); c += bt.d[0].nblks;
    bt.d[1] = mkD(Mb2, 0, 0, 1024, nullptr, nullptr, nullptr, Wa_bot, 128, 1025, 128, 1024, nullptr, nullptr, nullptr, nullptr, YTs(4), 1024, zbr(4), c); c += bt.d[1].nblks;
    for (int s = 1; s <= 3; ++s) {
      bt.d[1 + s] = mkD(Mb2, 0, 0, 1024, nullptr, nullptr, YTs(s), nullptr, 1024, 1025, 128, 1024, zbr(s), nullptr, nullptr, nullptr, YTs(4 + s), 1024, zbr(4 + s), c);
      c += bt.d[1 + s].nblks;
    }
    bt.nd = 5;
    gemmz<<<dim3(c), dim3(256), 0, stream>>>(bt);
  }
  // L4: M16, Z8, g1
  {
    GBatch bt{}; int c = 0;
    bt.d[0] = mkD(Mb3, 0, 0, 1024, nullptr, nullptr, Mb3T, nullptr, 1024, 1025, 1024, 1024, brow8, nullptr, nullptr, Mb1, Mb1T, 1024, brow16, c); c += bt.d[0].nblks;
    bt.d[1] = mkD(Mb3, 0, 0, 1024, nullptr, nullptr, nullptr, Wa_bot, 128, 1025, 128, 1024, nullptr, nullptr, nullptr, nullptr, YTs(8), 1024, zbr(8), c); c += bt.d[1].nblks;
    bt.d[2] = mkD(context, 1, 2, 1024, nullptr, nullptr, Mb3T, nullptr, 1024, 8, 1024, 1024, nullptr, brow8, nullptr, Gb + 8192, nullptr, 0, nullptr, c); c += bt.d[2].nblks;
    bt.nd = 3;
    gemmz<<<dim3(c), dim3(256), 0, stream>>>(bt);
  }
  // L5: M32, g2, g3, qH(k=0, r=1..8)
  {
    GBatch bt{}; int c = 0;
    bt.d[0] = mkD(Mb1, 0, 0, 1024, nullptr, nullptr, Mb1T, nullptr, 1024, 1025, 1024, 1024, brow16, nullptr, nullptr, Mb2, Mb2T, 1024, brow32, c); c += bt.d[0].nblks;
    bt.d[1] = mkD(context, 1, 2, 1024, nullptr, nullptr, Mb1T, nullptr, 1024, 8, 1024, 1024, nullptr, brow16, nullptr, Gb + 16384, nullptr, 0, nullptr, c); c += bt.d[1].nblks;
    bt.d[2] = mkD(Gb + 8192, 0, 0, 1024, nullptr, nullptr, Mb1T, nullptr, 1024, 8, 1024, 1024, nullptr, brow16, nullptr, Gb + 24576, nullptr, 0, nullptr, c); c += bt.d[2].nblks;
    for (int r = 1; r <= 8; ++r) {
      bt.d[2 + r] = mkD(context, 1, 2, 1024, nullptr, nullptr, YTs(r), nullptr, 1024, 8, 128, 1024, nullptr, zbr(r), qH + (long)(r - 1) * 8192, nullptr, nullptr, 0, nullptr, c);
      c += bt.d[2 + r].nblks;
    }
    bt.nd = 11;
    gemmz<<<dim3(c), dim3(256), 0, stream>>>(bt);
  }
  // L6: g4..g7, qH(k=1..3, r=1..8)
  {
    GBatch bt{}; int c = 0;
    bt.d[0] = mkD(context, 1, 2, 1024, nullptr, nullptr, Mb2T, nullptr, 1024, 8, 1024, 1024, nullptr, brow32, nullptr, Gb + 32768, nullptr, 0, nullptr, c); c += bt.d[0].nblks;
    bt.d[1] = mkD(Gb + 8192, 0, 0, 1024, nullptr, nullptr, Mb2T, nullptr, 1024, 8, 1024, 1024, nullptr, brow32, nullptr, Gb + 40960, nullptr, 0, nullptr, c); c += bt.d[1].nblks;
    bt.d[2] = mkD(Gb + 16384, 0, 0, 1024, nullptr, nullptr, Mb2T, nullptr, 1024, 8, 1024, 1024, nullptr, brow32, nullptr, Gb + 49152, nullptr, 0, nullptr, c); c += bt.d[2].nblks;
    bt.d[3] = mkD(Gb + 24576, 0, 0, 1024, nullptr, nullptr, Mb2T, nullptr, 1024, 8, 1024, 1024, nullptr, brow32, nullptr, Gb + 57344, nullptr, 0, nullptr, c); c += bt.d[3].nblks;
    for (int r = 1; r <= 8; ++r) {
      bt.d[3 + r] = mkD(Gb + 8192, 0, 0, 1024, nullptr, nullptr, YTs(r), nullptr, 1024, 24, 128, 1024, nullptr, zbr(r), qH + (long)(r - 1) * 8192 + 1024, nullptr, nullptr, 0, nullptr, c);
      c += bt.d[3 + r].nblks;
    }
    bt.nd = 12;
    gemmz<<<dim3(c), dim3(256), 0, stream>>>(bt);
  }
  // L7: qH(k=4..7, r=1..8)
  {
    GBatch bt{}; int c = 0;
    for (int r = 1; r <= 8; ++r) {
      bt.d[r - 1] = mkD(Gb + 32768, 0, 0, 1024, nullptr, nullptr, YTs(r), nullptr, 1024, 32, 128, 1024, nullptr, zbr(r), qH + (long)(r - 1) * 8192 + 4096, nullptr, nullptr, 0, nullptr, c);
      c += bt.d[r - 1].nblks;
    }
    bt.nd = 8;
    gemmz<<<dim3(c), dim3(256), 0, stream>>>(bt);
  }
  katt<<<dim3(256), dim3(256), 0, stream>>>(qF, qH, ctxp, V, out);
}

// Round 13
// 156.841 us; speedup vs baseline: 8.2261x; 1.3412x over previous
//
#include <hip/hip_runtime.h>
#include <hip/hip_bf16.h>

#define EMB 768
#define HD 1024
#define D3 128
#define CTXN 512
#define BB 8
#define SS 64

typedef __hip_bfloat16 bf16;
typedef __attribute__((ext_vector_type(8))) short short8v;
typedef __attribute__((ext_vector_type(4))) float f32x4;

__device__ __forceinline__ float fast_tanh(float x) {
  float e = __expf(2.f * x);
  return 1.f - 2.f * __builtin_amdgcn_rcpf(e + 1.f);
}

struct GDesc {
  const void* A;                 // row-major [M][K], fp32 or bf16
  const bf16* BT;                // transposed B: [N][K] bf16
  const int* arowmap;            // optional A row gather
  const float* addrow_f;         // added to row M-1 only (affine-aug compose)
  const float* bias_f;           // added to all rows
  float* Cf;                     // fp32 row-major out
  bf16* Cb;                      // bf16 row-major out
  bf16* CbT;                     // bf16 transposed out [N][ldct], rows<1024 only
  float* brow_f;                 // fp32 copy of row M-1
  int M, N, K, lda, ldbt, ldct, af32, mtiles, blk0, nblks;
};
struct GBatch { GDesc d[10]; int nd; };

// gemmz: 32x64 tile, BK=128, 4 waves (each 16x32), XOR-swizzled LDS, dbuf.
// XCD-chunked bijective block swizzle: consecutive logical tiles (same B panel,
// since tile id = mt + nt*mtiles) land on one XCD's L2.
__global__ __launch_bounds__(256) void gemmz(GBatch bat) {
  int nwg = gridDim.x, orig = blockIdx.x;
  int q8 = nwg >> 3, r8 = nwg & 7;
  int xcd = orig & 7, idx = orig >> 3;
  int bx = (xcd < r8 ? xcd * (q8 + 1) : r8 * (q8 + 1) + (xcd - r8) * q8) + idx;

  GDesc d = bat.d[0];
  for (int i = 1; i < bat.nd; ++i)
    if (bx >= bat.d[i].blk0) d = bat.d[i];
  int local = bx - d.blk0;
  int mt = local % d.mtiles, nt = local / d.mtiles;
  int bm0 = mt * 32, bn0 = nt * 64;

  __shared__ bf16 As[2][32][128];  // swizzled: 16B-chunk ^ (row&7)
  __shared__ bf16 Bs[2][64][128];
  int tid = threadIdx.x, lane = tid & 63, wid = tid >> 6;
  int l16 = lane & 15, g = lane >> 4;
  int wm = (wid & 1) * 16, wn = (wid >> 1) * 32;
  int arow = tid >> 3, aseg = tid & 7;  // A: 32 rows, 16 el/thread
  int brow = tid >> 2, bseg = tid & 3;  // B: 64 rows, 32 el/thread
  f32x4 acc[2] = {};

  int agr = bm0 + arow;
  int asrc = (agr < d.M) ? (d.arowmap ? d.arowmap[agr] : agr) : -1;
  const float* Af = (const float*)d.A;
  const bf16* Ab = (const bf16*)d.A;

  float fa[16];
  short8v ba0 = {}, ba1 = {}, bb0 = {}, bb1 = {}, bb2 = {}, bb3 = {};
  int nk = d.K >> 7;

  auto LD = [&](int k0) {
    if (d.af32) {
      if (asrc >= 0) {
        const float* s = Af + (long)asrc * d.lda + k0 + aseg * 16;
#pragma unroll
        for (int j = 0; j < 16; ++j) fa[j] = s[j];
      } else {
#pragma unroll
        for (int j = 0; j < 16; ++j) fa[j] = 0.f;
      }
    } else {
      if (asrc >= 0) {
        const bf16* s = Ab + (long)asrc * d.lda + k0 + aseg * 16;
        ba0 = *(const short8v*)s;
        ba1 = *(const short8v*)(s + 8);
      } else {
        short8v z = {};
        ba0 = z; ba1 = z;
      }
    }
    const bf16* bsrc = d.BT + (long)(bn0 + brow) * d.ldbt + k0 + bseg * 32;
    bb0 = *(const short8v*)bsrc;
    bb1 = *(const short8v*)(bsrc + 8);
    bb2 = *(const short8v*)(bsrc + 16);
    bb3 = *(const short8v*)(bsrc + 24);
  };
  auto ST = [&](int buf) {
    int rs = arow & 7;
    if (d.af32) {
      bf16 t8[16];
#pragma unroll
      for (int j = 0; j < 16; ++j) t8[j] = __float2bfloat16(fa[j]);
      *(short8v*)&As[buf][arow][((2 * aseg) ^ rs) * 8] = *(short8v*)t8;
      *(short8v*)&As[buf][arow][((2 * aseg + 1) ^ rs) * 8] = *(short8v*)(t8 + 8);
    } else {
      *(short8v*)&As[buf][arow][((2 * aseg) ^ rs) * 8] = ba0;
      *(short8v*)&As[buf][arow][((2 * aseg + 1) ^ rs) * 8] = ba1;
    }
    int rb = brow & 7;
    *(short8v*)&Bs[buf][brow][((4 * bseg) ^ rb) * 8] = bb0;
    *(short8v*)&Bs[buf][brow][((4 * bseg + 1) ^ rb) * 8] = bb1;
    *(short8v*)&Bs[buf][brow][((4 * bseg + 2) ^ rb) * 8] = bb2;
    *(short8v*)&Bs[buf][brow][((4 * bseg + 3) ^ rb) * 8] = bb3;
  };

  LD(0);
  ST(0);
  __syncthreads();
  for (int it = 0; it < nk; ++it) {
    int cur = it & 1;
    if (it + 1 < nk) LD((it + 1) << 7);
    int ar = wm + l16;
    int ars = ar & 7;
#pragma unroll
    for (int kf = 0; kf < 4; ++kf) {
      short8v a = *(const short8v*)&As[cur][ar][((kf * 4 + g) ^ ars) * 8];
#pragma unroll
      for (int j = 0; j < 2; ++j) {
        int br = wn + j * 16 + l16;
        short8v b = *(const short8v*)&Bs[cur][br][((kf * 4 + g) ^ (br & 7)) * 8];
        acc[j] = __builtin_amdgcn_mfma_f32_16x16x32_bf16(a, b, acc[j], 0, 0, 0);
      }
    }
    if (it + 1 < nk) ST(cur ^ 1);
    __syncthreads();
  }

  // epilogue (final loop sync passed: LDS free)
  float* Cs = (float*)&Bs[0][0][0];  // [64][33] floats = 8448 B
  bool doT = (d.CbT != nullptr);
#pragma unroll
  for (int j = 0; j < 2; ++j)
#pragma unroll
    for (int r = 0; r < 4; ++r) {
      int gl = wm + g * 4 + r, cl = wn + j * 16 + l16;
      int grow = bm0 + gl, gcol = bn0 + cl;
      float v = acc[j][r];
      if (d.bias_f) v += d.bias_f[gcol];
      if (d.addrow_f && grow == d.M - 1) v += d.addrow_f[gcol];
      if (grow < d.M) {
        if (d.Cf) d.Cf[(long)grow * d.N + gcol] = v;
        if (d.Cb) d.Cb[(long)grow * d.N + gcol] = __float2bfloat16(v);
        if (d.brow_f && grow == d.M - 1) d.brow_f[gcol] = v;
      }
      if (doT) Cs[cl * 33 + gl] = v;
    }
  if (doT) {
    __syncthreads();
    int ctrows = d.M < 1024 ? d.M : 1024;
    int n = tid >> 2, ms = (tid & 3) * 8;
    int gm0 = bm0 + ms;
    bf16 t8[8];
#pragma unroll
    for (int jj = 0; jj < 8; ++jj) t8[jj] = __float2bfloat16(Cs[n * 33 + ms + jj]);
    if (gm0 + 7 < ctrows) {
      *(short8v*)&d.CbT[(long)(bn0 + n) * d.ldct + gm0] = *(short8v*)t8;
    } else {
#pragma unroll
      for (int jj = 0; jj < 8; ++jj)
        if (gm0 + jj < ctrows) d.CbT[(long)(bn0 + n) * d.ldct + gm0 + jj] = t8[jj];
    }
  }
}

// kcast: Maug1 bf16, transposes, g0, qb, rowmap, ctx bf16
__global__ __launch_bounds__(256) void kcast(const float* __restrict__ W_s,
                                             const float* __restrict__ b_s,
                                             const float* __restrict__ context,
                                             const float* __restrict__ b_in,
                                             const float* __restrict__ W_att_in,
                                             const float* __restrict__ b_att_in,
                                             const float* __restrict__ W_att_h,
                                             const int* __restrict__ ids,
                                             bf16* __restrict__ Mb0,
                                             bf16* __restrict__ Mb0T,
                                             bf16* __restrict__ Y0T,
                                             bf16* __restrict__ WahT,
                                             bf16* __restrict__ WaiT,
                                             bf16* __restrict__ Gb,
                                             float* __restrict__ qb,
                                             int* __restrict__ rowmap,
                                             bf16* __restrict__ ctxb) {
  int blk = blockIdx.x, tid = threadIdx.x;
  __shared__ bf16 tl[64][65];
  __shared__ float red[2][128];

  auto TP = [&](const float* src, int R, int C, bf16* dst, int tr, int tc) {
    int r0 = tr * 64, c0 = tc * 64;
    {
      int r = tid >> 2, cs = (tid & 3) * 16;
      const float* s = src + (long)(r0 + r) * C + c0 + cs;
#pragma unroll
      for (int j = 0; j < 16; ++j) tl[cs + j][r] = __float2bfloat16(s[j]);
    }
    __syncthreads();
    {
      int c = tid >> 2, rs = (tid & 3) * 16;
      bf16 o[16];
#pragma unroll
      for (int j = 0; j < 16; ++j) o[j] = tl[c][rs + j];
      *(short8v*)&dst[(long)(c0 + c) * R + r0 + rs] = *(short8v*)&o[0];
      *(short8v*)&dst[(long)(c0 + c) * R + r0 + rs + 8] = *(short8v*)&o[8];
    }
  };

  if (blk < 256) {
    long base = (long)blk * 4096;
    for (int i = tid; i < 4096; i += 256)
      Mb0[base + i] = __float2bfloat16(W_s[base + i]);
  } else if (blk == 256) {
    for (int i = tid; i < HD; i += 256)
      Mb0[(long)HD * HD + i] = __float2bfloat16(b_s[i]);
  } else if (blk < 513) {
    int t = blk - 257;
    TP(W_s, 1024, 1024, Mb0T, t >> 4, t & 15);
  } else if (blk < 545) {
    int t = blk - 513;
    TP(W_att_in + (long)1024 * D3, 1024, 128, Y0T, t >> 1, t & 1);
  } else if (blk < 577) {
    int t = blk - 545;
    TP(W_att_h, 1024, 128, WahT, t >> 1, t & 1);
  } else if (blk < 609) {
    int t = blk - 577;
    TP(W_att_in, 1024, 128, WaiT, t >> 1, t & 1);
  } else if (blk == 609) {
    for (int i = tid; i < BB * HD; i += 256) {
      int b = i >> 10, k = i & 1023;
      Gb[i] = __float2bfloat16(context[((long)b * CTXN + CTXN - 1) * HD + k]);
    }
  } else if (blk == 610) {
    int dd = tid & 127, h = tid >> 7;
    float acc = 0.f;
    for (int k = h * 512; k < h * 512 + 512; ++k)
      acc += b_in[k] * W_att_in[k * D3 + dd];
    red[h][dd] = acc;
    __syncthreads();
    if (h == 0) qb[dd] = red[0][dd] + red[1][dd] + b_att_in[dd];
  } else if (blk == 611) {
    for (int i = tid; i < 512; i += 256) {
      int t = i >> 3, b = i & 7;
      rowmap[i] = ids[b * SS + t];
    }
  } else {
    // blocks 612..1635: context -> bf16, 4096 elems per block, float4-vectorized
    long base = (long)(blk - 612) * 4096;
    const float4* src = (const float4*)(context + base);
    int f0 = tid * 4;
    float4 v0 = src[f0], v1 = src[f0 + 1], v2 = src[f0 + 2], v3 = src[f0 + 3];
    bf16 o[16];
    o[0] = __float2bfloat16(v0.x); o[1] = __float2bfloat16(v0.y);
    o[2] = __float2bfloat16(v0.z); o[3] = __float2bfloat16(v0.w);
    o[4] = __float2bfloat16(v1.x); o[5] = __float2bfloat16(v1.y);
    o[6] = __float2bfloat16(v1.z); o[7] = __float2bfloat16(v1.w);
    o[8] = __float2bfloat16(v2.x); o[9] = __float2bfloat16(v2.y);
    o[10] = __float2bfloat16(v2.z); o[11] = __float2bfloat16(v2.w);
    o[12] = __float2bfloat16(v3.x); o[13] = __float2bfloat16(v3.y);
    o[14] = __float2bfloat16(v3.z); o[15] = __float2bfloat16(v3.w);
    *(short8v*)&ctxb[base + tid * 16] = *(short8v*)&o[0];
    *(short8v*)&ctxb[base + tid * 16 + 8] = *(short8v*)&o[8];
  }
}

// katt: out[b][t][c] = sum_d V[d]*tanh(qF[t*8+b][d] + qH[t&7][(t>>3)*8+b][d] + ctxp[b][c][d])
__global__ __launch_bounds__(256) void katt(const float* __restrict__ qF,
                                            const float* __restrict__ qH,
                                            const float* __restrict__ ctxp,
                                            const float* __restrict__ V,
                                            float* __restrict__ out) {
  int blk = blockIdx.x;
  int b = blk >> 5, tt = (blk >> 4) & 1, ct = blk & 15;
  int t0 = tt * 32, c0 = ct * 32;
  int tid = threadIdx.x;
  __shared__ float lq[32][128];
  __shared__ float lc[32][132];
  __shared__ float lv[128];
  for (int i = tid; i < 32 * 128; i += 256) {
    int r = i >> 7, d = i & 127;
    int t = t0 + r;
    lq[r][d] = qF[((long)t * 8 + b) * 128 + d] +
               qH[(((long)(t & 7)) * 64 + (t >> 3) * 8 + b) * 128 + d];
    lc[r][d] = ctxp[((long)b * CTXN + c0 + r) * D3 + d];
  }
  if (tid < 128) lv[tid] = V[tid];
  __syncthreads();
  int cl = tid & 31, tg = tid >> 5;
  float r4[4] = {0.f, 0.f, 0.f, 0.f};
  for (int d4 = 0; d4 < 32; ++d4) {
    float4 cv = *reinterpret_cast<const float4*>(&lc[cl][d4 * 4]);
    float4 vv = *reinterpret_cast<const float4*>(&lv[d4 * 4]);
#pragma unroll
    for (int u = 0; u < 4; ++u) {
      int t = tg + u * 8;
      float4 qv = *reinterpret_cast<const float4*>(&lq[t][d4 * 4]);
      r4[u] = fmaf(vv.x, fast_tanh(qv.x + cv.x), r4[u]);
      r4[u] = fmaf(vv.y, fast_tanh(qv.y + cv.y), r4[u]);
      r4[u] = fmaf(vv.z, fast_tanh(qv.z + cv.z), r4[u]);
      r4[u] = fmaf(vv.w, fast_tanh(qv.w + cv.w), r4[u]);
    }
  }
#pragma unroll
  for (int u = 0; u < 4; ++u) {
    int t = tg + u * 8;
    out[((long)b * SS + (t0 + t)) * CTXN + c0 + cl] = r4[u];
  }
  if (blk == 0) {
    for (int i = tid; i < SS * BB; i += 256) out[(long)BB * SS * CTXN + i] = 0.f;
  }
}

static inline GDesc mk(const void* A, int af32, int lda, const int* arowmap,
                       const bf16* BT, int ldbt, int M, int N, int K,
                       const float* addrow_f, const float* bias_f, float* Cf,
                       bf16* Cb, bf16* CbT, int ldct, float* brow_f, int blk0) {
  GDesc d;
  d.A = A; d.BT = BT; d.arowmap = arowmap;
  d.addrow_f = addrow_f; d.bias_f = bias_f;
  d.Cf = Cf; d.Cb = Cb; d.CbT = CbT; d.brow_f = brow_f;
  d.M = M; d.N = N; d.K = K; d.lda = lda; d.ldbt = ldbt; d.ldct = ldct;
  d.af32 = af32;
  d.mtiles = (M + 31) >> 5;
  d.blk0 = blk0;
  d.nblks = d.mtiles * (N >> 6);
  return d;
}

extern "C" void kernel_launch(void* const* d_in, const int* in_sizes, int n_in,
                              void* d_out, int out_size, void* d_ws, size_t ws_size,
                              hipStream_t stream) {
  const int* ids = (const int*)d_in[0];
  const float* context = (const float*)d_in[4];
  const float* emb = (const float*)d_in[5];
  const float* W_in = (const float*)d_in[6];
  const float* b_in = (const float*)d_in[7];
  const float* W_s = (const float*)d_in[8];
  const float* b_s = (const float*)d_in[9];
  const float* W_att_in = (const float*)d_in[10];
  const float* b_att_in = (const float*)d_in[11];
  const float* W_att_h = (const float*)d_in[12];
  const float* b_att_h = (const float*)d_in[13];
  const float* V = (const float*)d_in[14];

  float* ws = (float*)d_ws;
  float* ctxp = ws;                     // 524288
  float* Yf = ctxp + 524288;            // 9*131200 (slot r, r=0 unused)
  float* qF = Yf + 1180800;             // 65536
  float* qH = qF + 65536;               // 65536
  float* qb = qH + 65536;               // 128
  float* brow2 = qb + 128;              // 1024 each
  float* brow4 = brow2 + 1024;
  float* brow8 = brow4 + 1024;
  float* brow16 = brow8 + 1024;
  float* brow32 = brow16 + 1024;
  int* rowmap = (int*)(brow32 + 1024);  // 512
  bf16* bfp = (bf16*)(rowmap + 512);
  bf16* Mb0 = bfp;                      // 1025*1024
  bf16* Mb0T = Mb0 + 1049600;           // 1024*1024
  bf16* Mb1 = Mb0T + 1048576;
  bf16* Mb1T = Mb1 + 1049600;
  bf16* Mb2 = Mb1T + 1048576;
  bf16* Mb2T = Mb2 + 1049600;
  bf16* Mb3 = Mb2T + 1048576;
  bf16* Mb3T = Mb3 + 1049600;
  bf16* YT = Mb3T + 1048576;            // 9 slots * 131072
  bf16* WahT = YT + 9 * 131072;
  bf16* WaiT = WahT + 131072;
  bf16* WcT = WaiT + 131072;            // [128][768]
  bf16* Gb = WcT + 131072;              // 64*1024
  bf16* ctxb = Gb + 65536;              // [4096][1024]
  float* out = (float*)d_out;

  auto Yfr = [&](int r) { return Yf + (long)r * 131200; };
  auto YTs = [&](int r) { return YT + (long)r * 131072; };

  kcast<<<dim3(1636), dim3(256), 0, stream>>>(W_s, b_s, context, b_in, W_att_in,
                                              b_att_in, W_att_h, ids, Mb0, Mb0T,
                                              YTs(0), WahT, WaiT, Gb, qb, rowmap,
                                              ctxb);
  // L1: M2 = M1^2 ; Z1 = M1*Z0 ; ctx_proj (bf16 A) ; WcT
  {
    GBatch bt{}; int c = 0;
    bt.d[0] = mk(Mb0, 0, 1024, nullptr, Mb0T, 1024, 1025, 1024, 1024, b_s, nullptr, nullptr, Mb1, Mb1T, 1024, brow2, c); c += bt.d[0].nblks;
    bt.d[1] = mk(Mb0, 0, 1024, nullptr, YTs(0), 1024, 1025, 128, 1024, nullptr, nullptr, Yfr(1), nullptr, YTs(1), 1024, nullptr, c); c += bt.d[1].nblks;
    bt.d[2] = mk(ctxb, 0, 1024, nullptr, WahT, 1024, 4096, 128, 1024, nullptr, b_att_h, ctxp, nullptr, nullptr, 0, nullptr, c); c += bt.d[2].nblks;
    bt.d[3] = mk(W_in, 1, 1024, nullptr, WaiT, 1024, 768, 128, 1024, nullptr, nullptr, nullptr, nullptr, WcT, 768, nullptr, c); c += bt.d[3].nblks;
    bt.nd = 4;
    gemmz<<<dim3(c), dim3(256), 0, stream>>>(bt);
  }
  // L2: M4 ; Z2 ; Z3 ; qF = emb[rowmap]*Wc + qb
  {
    GBatch bt{}; int c = 0;
    bt.d[0] = mk(Mb1, 0, 1024, nullptr, Mb1T, 1024, 1025, 1024, 1024, brow2, nullptr, nullptr, Mb2, Mb2T, 1024, brow4, c); c += bt.d[0].nblks;
    bt.d[1] = mk(Mb1, 0, 1024, nullptr, YTs(0), 1024, 1025, 128, 1024, nullptr, nullptr, Yfr(2), nullptr, YTs(2), 1024, nullptr, c); c += bt.d[1].nblks;
    bt.d[2] = mk(Mb1, 0, 1024, nullptr, YTs(1), 1024, 1025, 128, 1024, Yfr(1) + 131072, nullptr, Yfr(3), nullptr, YTs(3), 1024, nullptr, c); c += bt.d[2].nblks;
    bt.d[3] = mk(emb, 1, 768, rowmap, WcT, 768, 512, 128, 768, nullptr, qb, qF, nullptr, nullptr, 0, nullptr, c); c += bt.d[3].nblks;
    bt.nd = 4;
    gemmz<<<dim3(c), dim3(256), 0, stream>>>(bt);
  }
  // L3: M8 ; Z4..Z7
  {
    GBatch bt{}; int c = 0;
    bt.d[0] = mk(Mb2, 0, 1024, nullptr, Mb2T, 1024, 1025, 1024, 1024, brow4, nullptr, nullptr, Mb3, Mb3T, 1024, brow8, c); c += bt.d[0].nblks;
    for (int s = 0; s < 4; ++s) {
      bt.d[1 + s] = mk(Mb2, 0, 1024, nullptr, YTs(s), 1024, 1025, 128, 1024,
                       (s == 0) ? nullptr : (Yfr(s) + 131072), nullptr,
                       Yfr(4 + s), nullptr, YTs(4 + s), 1024, nullptr, c);
      c += bt.d[1 + s].nblks;
    }
    bt.nd = 5;
    gemmz<<<dim3(c), dim3(256), 0, stream>>>(bt);
  }
  // L4: M16 ; Z8 ; g1 = g0*W8 + b8
  {
    GBatch bt{}; int c = 0;
    bt.d[0] = mk(Mb3, 0, 1024, nullptr, Mb3T, 1024, 1025, 1024, 1024, brow8, nullptr, nullptr, Mb1, Mb1T, 1024, brow16, c); c += bt.d[0].nblks;
    bt.d[1] = mk(Mb3, 0, 1024, nullptr, YTs(0), 1024, 1025, 128, 1024, nullptr, nullptr, Yfr(8), nullptr, YTs(8), 1024, nullptr, c); c += bt.d[1].nblks;
    bt.d[2] = mk(Gb, 0, 1024, nullptr, Mb3T, 1024, 8, 1024, 1024, nullptr, brow8, nullptr, Gb + 8192, nullptr, 0, nullptr, c); c += bt.d[2].nblks;
    bt.nd = 3;
    gemmz<<<dim3(c), dim3(256), 0, stream>>>(bt);
  }
  // L5: M32 ; [g2,g3] = [g0,g1]*W16 + b16
  {
    GBatch bt{}; int c = 0;
    bt.d[0] = mk(Mb1, 0, 1024, nullptr, Mb1T, 1024, 1025, 1024, 1024, brow16, nullptr, nullptr, Mb2, Mb2T, 1024, brow32, c); c += bt.d[0].nblks;
    bt.d[1] = mk(Gb, 0, 1024, nullptr, Mb1T, 1024, 16, 1024, 1024, nullptr, brow16, nullptr, Gb + 16384, nullptr, 0, nullptr, c); c += bt.d[1].nblks;
    bt.nd = 2;
    gemmz<<<dim3(c), dim3(256), 0, stream>>>(bt);
  }
  // L6: [g4..g7] = [g0..g3]*W32 + b32
  {
    GBatch bt{}; int c = 0;
    bt.d[0] = mk(Gb, 0, 1024, nullptr, Mb2T, 1024, 32, 1024, 1024, nullptr, brow32, nullptr, Gb + 32768, nullptr, 0, nullptr, c); c += bt.d[0].nblks;
    bt.nd = 1;
    gemmz<<<dim3(c), dim3(256), 0, stream>>>(bt);
  }
  // L7: qH_r = G*Z_r + c_r (r=1..8)
  {
    GBatch bt{}; int c = 0;
    for (int r = 1; r <= 8; ++r) {
      bt.d[r - 1] = mk(Gb, 0, 1024, nullptr, YTs(r), 1024, 64, 128, 1024, nullptr,
                       Yfr(r) + 131072, qH + (long)(r - 1) * 8192, nullptr, nullptr,
                       0, nullptr, c);
      c += bt.d[r - 1].nblks;
    }
    bt.nd = 8;
    gemmz<<<dim3(c), dim3(256), 0, stream>>>(bt);
  }
  katt<<<dim3(256), dim3(256), 0, stream>>>(qF, qH, ctxp, V, out);
}